// Round 7
// baseline (253.426 us; speedup 1.0000x reference)
//
#include <hip/hip_runtime.h>
#include <hip/hip_bf16.h>

typedef __attribute__((ext_vector_type(8))) short short8;
typedef __attribute__((ext_vector_type(4))) float floatx4;

#define N_ROWS   16384
#define IN_DIM   512
#define OUT_DIM  512
#define K_SPLINE 4096
#define K_TOT    4608
#define NPER     36              /* 128-k barrier periods */
#define NSPER    32              /* spline periods (4096/128) */
#define NKTILE   144             /* 32-wide k-tiles */
#define ROWS_B   128             /* rows per block */
#define COLS_B   256             /* cols per block (d=2 duplication) */
#define L2E      1.4426950408889634f
#define C2E      0.13533528323661270f   /* exp(-2) */

__device__ __forceinline__ unsigned short f2bf(float f) {
    unsigned int u = __float_as_uint(f);
    unsigned int r = u + 0x7FFFu + ((u >> 16) & 1u);
    return (unsigned short)(r >> 16);
}

// truncating pack: two fp32 -> two bf16 in one v_perm_b32 (A-side only; B rounded in prep)
__device__ __forceinline__ unsigned packtrunc(float f0, float f1) {
    return __builtin_amdgcn_perm(__float_as_uint(f1), __float_as_uint(f0), 0x07060302);
}

// lgkm-only barrier: staging ds_writes drained (visibility) and own ds_reads
// drained (WAR safety), but global loads stay IN FLIGHT across the barrier
// (compiler inserts counted vmcnt before each use of their dest VGPRs).
__device__ __forceinline__ void barrier_lgkm() {
    asm volatile("s_waitcnt lgkmcnt(0)\n\ts_barrier" ::: "memory");
}

// ---------------------------------------------------------------------------
// prep: B in MFMA B-fragment-tiled layout (16x16x32) — unchanged.
// frag idx = (ct*NKTILE + kt32)*64 + lane ; elem j:
//   n = ct*16 + (lane&15), k = kt32*32 + (lane>>4)*8 + j
// ---------------------------------------------------------------------------
__global__ __launch_bounds__(256) void prep_kernel(
    const float* __restrict__ sw, const float* __restrict__ bw,
    unsigned short* __restrict__ Btf)
{
    const int t     = threadIdx.x;
    const int lane  = t & 63;
    const int kt32  = blockIdx.x * 4 + (t >> 6);
    const int ct    = blockIdx.y;
    const int mn    = lane & 15, q = lane >> 4;
    const int n     = ct * 16 + mn;
    const int kbase = kt32 * 32 + q * 8;
    short8 v;
    if (kbase < K_SPLINE) {
        #pragma unroll
        for (int j = 0; j < 8; ++j)
            v[j] = (short)f2bf(sw[(size_t)(kbase + j) * OUT_DIM + n]);
    } else {
        #pragma unroll
        for (int j = 0; j < 8; ++j)
            v[j] = (short)f2bf(bw[(size_t)n * IN_DIM + (kbase + j - K_SPLINE)]);
    }
    reinterpret_cast<short8*>(Btf)[(size_t)(ct * NKTILE + kt32) * 64 + lane] = v;
}

// ---------------------------------------------------------------------------
// 8 basis values of one x -> packed uint4 (bf16 x8)
// ---------------------------------------------------------------------------
__device__ __forceinline__ uint4 basis_pack(float X) {
    const float u = fmaf(1.75f, X, 3.5f);
    float b = __builtin_amdgcn_exp2f(-(u * u) * L2E);            // exp(-u^2)
    float r = __builtin_amdgcn_exp2f(fmaf(2.0f * L2E, u, -L2E)); // exp(2u-1)
    float v[8];
    v[0] = b;
    #pragma unroll
    for (int j = 1; j < 8; ++j) { b *= r; r *= C2E; v[j] = b; }
    uint4 p;
    p.x = packtrunc(v[0], v[1]);
    p.y = packtrunc(v[2], v[3]);
    p.z = packtrunc(v[4], v[5]);
    p.w = packtrunc(v[6], v[7]);
    return p;
}

// ---------------------------------------------------------------------------
// Stage one 128x128 A-tile (period p) into swizzled LDS — 512-thread map.
// Row stride 128 ushort (256B); 16B blocks, stored blk = i ^ (row&15).
// Thread: rowA = tid>>2 (0..127), colq = tid&3, covers blocks colq*4+e, e=0..3.
// ---------------------------------------------------------------------------
__device__ __forceinline__ void stageA128(unsigned short* dst, const float* xrow,
                                          int rowA, int colq, int p, float4 xsp)
{
    unsigned short* arow = dst + rowA * 128;
    if (p < NSPER) {
        const float xv[4] = {xsp.x, xsp.y, xsp.z, xsp.w};
        #pragma unroll
        for (int e = 0; e < 4; ++e) {
            const uint4 pk = basis_pack(xv[e]);
            const int blk = (colq * 4 + e) ^ (rowA & 15);
            *reinterpret_cast<uint4*>(arow + blk * 8) = pk;
        }
    } else {
        const float* xs = xrow + (p - NSPER) * 128 + colq * 32;
        #pragma unroll
        for (int e = 0; e < 4; ++e) {
            const float4 a0 = *reinterpret_cast<const float4*>(xs + e * 8);
            const float4 a1 = *reinterpret_cast<const float4*>(xs + e * 8 + 4);
            const float f[8] = {a0.x, a0.y, a0.z, a0.w, a1.x, a1.y, a1.z, a1.w};
            float s[8];
            #pragma unroll
            for (int j = 0; j < 8; ++j)
                s[j] = f[j] * __builtin_amdgcn_rcpf(
                    1.0f + __builtin_amdgcn_exp2f(-f[j] * L2E));
            uint4 pk;
            pk.x = packtrunc(s[0], s[1]);
            pk.y = packtrunc(s[2], s[3]);
            pk.z = packtrunc(s[4], s[5]);
            pk.w = packtrunc(s[6], s[7]);
            const int blk = (colq * 4 + e) ^ (rowA & 15);
            *reinterpret_cast<uint4*>(arow + blk * 8) = pk;
        }
    }
}

// B fragments for one period: this wave's 2 k-steps (kh*2+s) x 4 nt.
template<bool PREP>
__device__ __forceinline__ void load_b(short8 (&bb)[4][2], const short8* __restrict__ Bf,
                                       const size_t* bbase, int p, int kh,
                                       const float* __restrict__ sw,
                                       const float* __restrict__ bw,
                                       int col0, int lane)
{
    if (PREP) {
        #pragma unroll
        for (int nt = 0; nt < 4; ++nt)
            #pragma unroll
            for (int s = 0; s < 2; ++s)
                bb[nt][s] = Bf[bbase[nt] + (size_t)(p * 4 + kh * 2 + s) * 64];
    } else {
        const int mn = lane & 15, q = lane >> 4;
        #pragma unroll
        for (int nt = 0; nt < 4; ++nt) {
            const int n = col0 + nt * 16 + mn;
            #pragma unroll
            for (int s = 0; s < 2; ++s) {
                short8 v;
                #pragma unroll
                for (int j = 0; j < 8; ++j) {
                    const int k = (p * 4 + kh * 2 + s) * 32 + q * 8 + j;
                    const float val = (k < K_SPLINE)
                        ? sw[(size_t)k * OUT_DIM + n]
                        : bw[(size_t)n * IN_DIM + (k - K_SPLINE)];
                    v[j] = (short)f2bf(val);
                }
                bb[nt][s] = v;
            }
        }
    }
}

// ---------------------------------------------------------------------------
// Fused KAN — R7: R6 geometry (grid 256, block 128x256, 8 waves = 2kh x 4wc,
// issued B 64KB/CU-period) + two period-deserializers:
//   (1) lgkm-only barrier: global loads stay in flight across periods
//       (no per-period vmcnt(0) drain);
//   (2) B reg-dbuf one FULL period ahead (load p+1 during p), static indices
//       via a p+=2 unrolled loop pair.
// ---------------------------------------------------------------------------
template<bool PREP>
__global__ __launch_bounds__(512, 2) void kan_kernel(
    const float* __restrict__ x,
    const unsigned short* __restrict__ Btf,
    const float* __restrict__ sw,
    const float* __restrict__ bw,
    const float* __restrict__ bias,
    float* __restrict__ out)
{
    __shared__ unsigned short Als[2][ROWS_B * 128];   // 2 x 32 KB

    const int tid  = threadIdx.x;
    const int w    = tid >> 6;          // 0..7
    const int lane = tid & 63;
    const int kh   = w >> 2;            // k-half of each period
    const int wc   = w & 3;             // 64-col group
    const int q    = lane >> 4;
    const int mn   = lane & 15;
    const int bid  = blockIdx.x;
    const int row0 = (bid >> 1) * ROWS_B;
    const int col0 = (bid & 1) * COLS_B + wc * 64;   // bid&1: XCD col-half

    const int rowA = tid >> 2;          // 0..127
    const int colq = tid & 3;           // 0..3
    const float* xrow = x + (size_t)(row0 + rowA) * IN_DIM;

    size_t bbase[4];
    #pragma unroll
    for (int nt = 0; nt < 4; ++nt)
        bbase[nt] = (size_t)(((col0 >> 4) + nt) * NKTILE) * 64 + lane;
    const short8* Bf = reinterpret_cast<const short8*>(Btf);

    floatx4 acc[8][4];
    #pragma unroll
    for (int i = 0; i < 8; ++i)
        #pragma unroll
        for (int j = 0; j < 4; ++j)
            acc[i][j] = (floatx4){0.f, 0.f, 0.f, 0.f};

    short8 bbA[4][2], bbB[4][2];        // B dbuf: named buffers, static indices

    // prologue: B for p=0 into bbA; stage p=0; spline x for p=1
    float4 xsp = *reinterpret_cast<const float4*>(xrow + colq * 4);
    load_b<PREP>(bbA, Bf, bbase, 0, kh, sw, bw, col0, lane);
    stageA128(&Als[0][0], xrow, rowA, colq, 0, xsp);
    xsp = *reinterpret_cast<const float4*>(xrow + 16 + colq * 4);
    __syncthreads();

    // one period: use bbu (loaded last period), load bbl for p+1, k-steps, barrier
    auto body = [&](int p, const unsigned short* Acur, unsigned short* Anxt,
                    short8 (&bbu)[4][2], short8 (&bbl)[4][2]) {
        if (p + 1 < NPER) {
            // B for NEXT period — a full period + one barrier of latency cover
            load_b<PREP>(bbl, Bf, bbase, p + 1, kh, sw, bw, col0, lane);
            stageA128(Anxt, xrow, rowA, colq, p + 1, xsp);
            if (p + 2 < NSPER)
                xsp = *reinterpret_cast<const float4*>(
                    xrow + (p + 2) * 16 + colq * 4);
        }
        #pragma unroll
        for (int s = 0; s < 2; ++s) {
            const int st = kh * 2 + s;      // this wave's 32-k step (0..3)
            #pragma unroll
            for (int mg = 0; mg < 2; ++mg) {   // mt-quads: af live = 16 VGPR
                short8 af[4];
                #pragma unroll
                for (int mt = 0; mt < 4; ++mt) {
                    const int r = (mg * 4 + mt) * 16 + mn;
                    af[mt] = *reinterpret_cast<const short8*>(
                        Acur + r * 128 + (((st * 4 + q) ^ (r & 15)) * 8));
                }
                __builtin_amdgcn_s_setprio(1);
                #pragma unroll
                for (int mt = 0; mt < 4; ++mt)
                    #pragma unroll
                    for (int nt = 0; nt < 4; ++nt)
                        acc[mg * 4 + mt][nt] = __builtin_amdgcn_mfma_f32_16x16x32_bf16(
                            af[mt], bbu[nt][s], acc[mg * 4 + mt][nt], 0, 0, 0);
                __builtin_amdgcn_s_setprio(0);
            }
        }
        barrier_lgkm();
    };

    #pragma unroll 1
    for (int p = 0; p < NPER; p += 2) {
        body(p,     &Als[0][0], &Als[1][0], bbA, bbB);
        body(p + 1, &Als[1][0], &Als[0][0], bbB, bbA);
    }

    // ------------------------------------------------------------------
    // epilogue: kh-pair reduction via LDS, two 64KB passes (fits Als).
    // ex idx: ((wc*4 + m)*4 + nt)*64 + lane  (4096 floatx4 = 64KB).
    // Pass 1: kh=1 ships acc[0..3]; kh=0 stores rows m*16 (m=0..3).
    // Pass 2: kh=0 ships acc[4..7]; kh=1 stores rows (4+m)*16.
    // ALL acc indices are literals inside wave-uniform branches (rule #20).
    // ------------------------------------------------------------------
    floatx4* ex = reinterpret_cast<floatx4*>(&Als[0][0]);
    if (kh) {
        #pragma unroll
        for (int m = 0; m < 4; ++m)
            #pragma unroll
            for (int nt = 0; nt < 4; ++nt)
                ex[((wc * 4 + m) * 4 + nt) * 64 + lane] = acc[m][nt];
    }
    __syncthreads();
    if (!kh) {
        #pragma unroll
        for (int nt = 0; nt < 4; ++nt) {
            const int col = col0 + nt * 16 + mn;
            const float bv = bias[col];
            #pragma unroll
            for (int m = 0; m < 4; ++m) {
                const floatx4 o  = acc[m][nt];
                const floatx4 r2 = ex[((wc * 4 + m) * 4 + nt) * 64 + lane];
                const int rb = row0 + m * 16 + q * 4;
                #pragma unroll
                for (int e = 0; e < 4; ++e)
                    out[(size_t)(rb + e) * OUT_DIM + col] = o[e] + r2[e] + bv;
            }
        }
    }
    __syncthreads();
    if (!kh) {
        #pragma unroll
        for (int m = 0; m < 4; ++m)
            #pragma unroll
            for (int nt = 0; nt < 4; ++nt)
                ex[((wc * 4 + m) * 4 + nt) * 64 + lane] = acc[4 + m][nt];
    }
    __syncthreads();
    if (kh) {
        #pragma unroll
        for (int nt = 0; nt < 4; ++nt) {
            const int col = col0 + nt * 16 + mn;
            const float bv = bias[col];
            #pragma unroll
            for (int m = 0; m < 4; ++m) {
                const floatx4 o  = acc[4 + m][nt];
                const floatx4 r2 = ex[((wc * 4 + m) * 4 + nt) * 64 + lane];
                const int rb = row0 + (4 + m) * 16 + q * 4;
                #pragma unroll
                for (int e = 0; e < 4; ++e)
                    out[(size_t)(rb + e) * OUT_DIM + col] = o[e] + r2[e] + bv;
            }
        }
    }
}

extern "C" void kernel_launch(void* const* d_in, const int* in_sizes, int n_in,
                              void* d_out, int out_size, void* d_ws, size_t ws_size,
                              hipStream_t stream)
{
    const float* x    = (const float*)d_in[0];
    // d_in[1] = grid (linspace(-2,2,8)) — folded into constants
    const float* sw   = (const float*)d_in[2];
    const float* bw   = (const float*)d_in[3];
    const float* bias = (const float*)d_in[4];
    float* out = (float*)d_out;

    const int nblk = (N_ROWS / ROWS_B) * (OUT_DIM / COLS_B);   // 256
    const size_t bt_bytes = (size_t)OUT_DIM * K_TOT * sizeof(unsigned short);
    if (ws_size >= bt_bytes) {
        unsigned short* Btf = (unsigned short*)d_ws;
        prep_kernel<<<dim3(NKTILE / 4, OUT_DIM / 16), 256, 0, stream>>>(sw, bw, Btf);
        kan_kernel<true><<<dim3(nblk), 512, 0, stream>>>(
            x, Btf, sw, bw, bias, out);
    } else {
        kan_kernel<false><<<dim3(nblk), 512, 0, stream>>>(
            x, nullptr, sw, bw, bias, out);
    }
}

// Round 8
// 158.312 us; speedup vs baseline: 1.6008x; 1.6008x over previous
//
#include <hip/hip_runtime.h>
#include <hip/hip_bf16.h>

typedef __attribute__((ext_vector_type(8))) short short8;
typedef __attribute__((ext_vector_type(4))) float floatx4;

#define N_ROWS   16384
#define IN_DIM   512
#define OUT_DIM  512
#define K_SPLINE 4096
#define K_TOT    4608
#define NKT      72              /* 64-k half-periods  */
#define NPER     36              /* 128-k barrier periods */
#define NSPER    32              /* spline periods (4096/128) */
#define NKTILE   144             /* 32-wide k-tiles */
#define L2E      1.4426950408889634f
#define C2E      0.13533528323661270f   /* exp(-2) */

__device__ __forceinline__ unsigned short f2bf(float f) {
    unsigned int u = __float_as_uint(f);
    unsigned int r = u + 0x7FFFu + ((u >> 16) & 1u);
    return (unsigned short)(r >> 16);
}

// truncating pack: two fp32 -> two bf16 in one v_perm_b32 (A-side only; B rounded in prep)
__device__ __forceinline__ unsigned packtrunc(float f0, float f1) {
    return __builtin_amdgcn_perm(__float_as_uint(f1), __float_as_uint(f0), 0x07060302);
}

// lgkm-only barrier (R8's single change vs R2): staging ds_writes drained
// (visibility) and own ds_reads drained (WAR safety), but wave-private global
// loads stay IN FLIGHT across the barrier — no per-period vmcnt(0) drain.
// Compiler inserts counted vmcnt before each use of the loaded VGPRs.
__device__ __forceinline__ void barrier_lgkm() {
    asm volatile("s_waitcnt lgkmcnt(0)\n\ts_barrier" ::: "memory");
}

// ---------------------------------------------------------------------------
// prep: B in MFMA B-fragment-tiled layout (16x16x32).
// frag idx = (ct*NKTILE + kt32)*64 + lane ; elem j:
//   n = ct*16 + (lane&15), k = kt32*32 + (lane>>4)*8 + j
// ---------------------------------------------------------------------------
__global__ __launch_bounds__(256) void prep_kernel(
    const float* __restrict__ sw, const float* __restrict__ bw,
    unsigned short* __restrict__ Btf)
{
    const int t     = threadIdx.x;
    const int lane  = t & 63;
    const int kt32  = blockIdx.x * 4 + (t >> 6);
    const int ct    = blockIdx.y;
    const int mn    = lane & 15, q = lane >> 4;
    const int n     = ct * 16 + mn;
    const int kbase = kt32 * 32 + q * 8;
    short8 v;
    if (kbase < K_SPLINE) {
        #pragma unroll
        for (int j = 0; j < 8; ++j)
            v[j] = (short)f2bf(sw[(size_t)(kbase + j) * OUT_DIM + n]);
    } else {
        #pragma unroll
        for (int j = 0; j < 8; ++j)
            v[j] = (short)f2bf(bw[(size_t)n * IN_DIM + (kbase + j - K_SPLINE)]);
    }
    reinterpret_cast<short8*>(Btf)[(size_t)(ct * NKTILE + kt32) * 64 + lane] = v;
}

// ---------------------------------------------------------------------------
// 8 basis values of one x -> packed uint4 (bf16 x8)
// ---------------------------------------------------------------------------
__device__ __forceinline__ uint4 basis_pack(float X) {
    const float u = fmaf(1.75f, X, 3.5f);
    float b = __builtin_amdgcn_exp2f(-(u * u) * L2E);            // exp(-u^2)
    float r = __builtin_amdgcn_exp2f(fmaf(2.0f * L2E, u, -L2E)); // exp(2u-1)
    float v[8];
    v[0] = b;
    #pragma unroll
    for (int j = 1; j < 8; ++j) { b *= r; r *= C2E; v[j] = b; }
    uint4 p;
    p.x = packtrunc(v[0], v[1]);
    p.y = packtrunc(v[2], v[3]);
    p.z = packtrunc(v[4], v[5]);
    p.w = packtrunc(v[6], v[7]);
    return p;
}

// ---------------------------------------------------------------------------
// Stage one 64x128 A-tile (period p) into swizzled LDS — 512-thread map.
// Row stride 128 ushort; 16B blocks, stored blk = i ^ (row&15).
// Thread covers row rowA = tid>>3, blocks i = colq*2, colq*2+1 (colq = tid&7).
//   spline period: 2 x-elems = the preloaded float2 xsp
//   silu  period: 16 consecutive x
// ---------------------------------------------------------------------------
__device__ __forceinline__ void stageA128(unsigned short* dst, const float* xrow,
                                          int rowA, int colq, int p, float2 xsp)
{
    unsigned short* arow = dst + rowA * 128;
    if (p < NSPER) {
        const float xv[2] = {xsp.x, xsp.y};
        #pragma unroll
        for (int e = 0; e < 2; ++e) {
            const uint4 pk = basis_pack(xv[e]);
            const int blk = (colq * 2 + e) ^ (rowA & 15);
            *reinterpret_cast<uint4*>(arow + blk * 8) = pk;
        }
    } else {
        const float* xs = xrow + (p - NSPER) * 128 + colq * 16;
        #pragma unroll
        for (int e = 0; e < 2; ++e) {
            const float4 a0 = *reinterpret_cast<const float4*>(xs + e * 8);
            const float4 a1 = *reinterpret_cast<const float4*>(xs + e * 8 + 4);
            const float f[8] = {a0.x, a0.y, a0.z, a0.w, a1.x, a1.y, a1.z, a1.w};
            float s[8];
            #pragma unroll
            for (int j = 0; j < 8; ++j)
                s[j] = f[j] * __builtin_amdgcn_rcpf(
                    1.0f + __builtin_amdgcn_exp2f(-f[j] * L2E));
            uint4 pk;
            pk.x = packtrunc(s[0], s[1]);
            pk.y = packtrunc(s[2], s[3]);
            pk.z = packtrunc(s[4], s[5]);
            pk.w = packtrunc(s[6], s[7]);
            const int blk = (colq * 2 + e) ^ (rowA & 15);
            *reinterpret_cast<uint4*>(arow + blk * 8) = pk;
        }
    }
}

// B fragment load for one 64-k half-period (kt): 4 nt x 2 s
template<bool PREP>
__device__ __forceinline__ void load_bfrags(short8 dst[4][2], const short8* __restrict__ Bf,
                                            const size_t* bbase, int kt,
                                            const float* __restrict__ sw,
                                            const float* __restrict__ bw,
                                            int col0, int lane)
{
    if (kt >= NKT) return;
    if (PREP) {
        #pragma unroll
        for (int nt = 0; nt < 4; ++nt)
            #pragma unroll
            for (int s = 0; s < 2; ++s)
                dst[nt][s] = Bf[bbase[nt] + (size_t)(kt * 2 + s) * 64];
    } else {
        const int mn = lane & 15, q = lane >> 4;
        #pragma unroll
        for (int nt = 0; nt < 4; ++nt) {
            const int n = col0 + nt * 16 + mn;
            #pragma unroll
            for (int s = 0; s < 2; ++s) {
                short8 v;
                #pragma unroll
                for (int j = 0; j < 8; ++j) {
                    const int k = (kt * 2 + s) * 32 + q * 8 + j;
                    const float val = (k < K_SPLINE)
                        ? sw[(size_t)k * OUT_DIM + n]
                        : bw[(size_t)n * IN_DIM + (k - K_SPLINE)];
                    v[j] = (short)f2bf(val);
                }
                dst[nt][s] = v;
            }
        }
    }
}

// ---------------------------------------------------------------------------
// Fused KAN — R2 machinery verbatim (best: 81 µs), ONE change: main-loop
// barrier is lgkm-only (no vmcnt drain). 256 blocks x 8 waves, block tile
// 64x512 (d=1: A staged once per x), wave tile 64x64, A LDS dbuf 2x16KB,
// B reg dbuf at 64-k half granularity, one barrier per 128-k period.
// ---------------------------------------------------------------------------
template<bool PREP>
__global__ __launch_bounds__(512, 2) void kan_kernel(
    const float* __restrict__ x,
    const unsigned short* __restrict__ Btf,
    const float* __restrict__ sw,
    const float* __restrict__ bw,
    const float* __restrict__ bias,
    float* __restrict__ out)
{
    __shared__ unsigned short Als[2][64 * 128];   // 2 x 16 KB

    const int tid  = threadIdx.x;
    const int wn   = tid >> 6;          // wave -> 64-col group (0..7)
    const int lane = tid & 63;
    const int q    = lane >> 4;
    const int mn   = lane & 15;
    const int bid  = blockIdx.x;
    const int row0 = bid * 64;
    const int col0 = wn * 64;

    const int rowA = tid >> 3;          // 0..63
    const int colq = tid & 7;           // 0..7
    const float* xrow = x + (size_t)(row0 + rowA) * IN_DIM;

    size_t bbase[4];
    #pragma unroll
    for (int nt = 0; nt < 4; ++nt)
        bbase[nt] = (size_t)(((col0 >> 4) + nt) * NKTILE) * 64 + lane;
    const short8* Bf = reinterpret_cast<const short8*>(Btf);

    floatx4 acc[4][4];
    #pragma unroll
    for (int i = 0; i < 4; ++i)
        #pragma unroll
        for (int j = 0; j < 4; ++j)
            acc[i][j] = (floatx4){0.f, 0.f, 0.f, 0.f};

    short8 bb[2][4][2];   // B dbuf, literal-indexed via unrolled hh

    // prologue: spline x for p=0, stage p=0, B for kt=0; prefetch x for p=1
    float2 xsp = *reinterpret_cast<const float2*>(xrow + colq * 2);
    stageA128(&Als[0][0], xrow, rowA, colq, 0, xsp);
    load_bfrags<PREP>(bb[0], Bf, bbase, 0, sw, bw, col0, lane);
    xsp = *reinterpret_cast<const float2*>(xrow + 16 + colq * 2);
    __syncthreads();

    for (int p = 0; p < NPER; ++p) {
        const unsigned short* Acur = &Als[p & 1][0];
        unsigned short*       Anxt = &Als[(p & 1) ^ 1][0];

        // B for second half of this period (kt = 2p+1)
        load_bfrags<PREP>(bb[1], Bf, bbase, 2 * p + 1, sw, bw, col0, lane);

        // stage A for period p+1 (overlaps this period's MFMA)
        if (p + 1 < NPER) {
            stageA128(Anxt, xrow, rowA, colq, p + 1, xsp);
            if (p + 2 < NSPER)
                xsp = *reinterpret_cast<const float2*>(
                    xrow + (p + 2) * 16 + colq * 2);
        }

        #pragma unroll
        for (int hh = 0; hh < 2; ++hh) {           // literal B-dbuf index
            #pragma unroll
            for (int s = 0; s < 2; ++s) {
                const int st = hh * 2 + s;
                short8 af[4];
                #pragma unroll
                for (int mt = 0; mt < 4; ++mt) {
                    const int r = mt * 16 + mn;
                    af[mt] = *reinterpret_cast<const short8*>(
                        Acur + r * 128 + (((st * 4 + q) ^ (r & 15)) * 8));
                }
                #pragma unroll
                for (int mt = 0; mt < 4; ++mt)
                    #pragma unroll
                    for (int nt = 0; nt < 4; ++nt)
                        acc[mt][nt] = __builtin_amdgcn_mfma_f32_16x16x32_bf16(
                            af[mt], bb[hh][nt][s], acc[mt][nt], 0, 0, 0);
            }
            // after consuming bb[0], prefetch first half of NEXT period into bb[0]
            if (hh == 0)
                load_bfrags<PREP>(bb[0], Bf, bbase, 2 * p + 2, sw, bw, col0, lane);
        }
        barrier_lgkm();
    }

    // epilogue: + bias, store fp32
    #pragma unroll
    for (int nt = 0; nt < 4; ++nt) {
        const int col = col0 + nt * 16 + mn;
        const float bv = bias[col];
        #pragma unroll
        for (int mt = 0; mt < 4; ++mt) {
            const int rb = row0 + mt * 16 + q * 4;
            #pragma unroll
            for (int e = 0; e < 4; ++e)
                out[(size_t)(rb + e) * OUT_DIM + col] = acc[mt][nt][e] + bv;
        }
    }
}

extern "C" void kernel_launch(void* const* d_in, const int* in_sizes, int n_in,
                              void* d_out, int out_size, void* d_ws, size_t ws_size,
                              hipStream_t stream)
{
    const float* x    = (const float*)d_in[0];
    // d_in[1] = grid (linspace(-2,2,8)) — folded into constants
    const float* sw   = (const float*)d_in[2];
    const float* bw   = (const float*)d_in[3];
    const float* bias = (const float*)d_in[4];
    float* out = (float*)d_out;

    const size_t bt_bytes = (size_t)OUT_DIM * K_TOT * sizeof(unsigned short);
    if (ws_size >= bt_bytes) {
        unsigned short* Btf = (unsigned short*)d_ws;
        prep_kernel<<<dim3(NKTILE / 4, OUT_DIM / 16), 256, 0, stream>>>(sw, bw, Btf);
        kan_kernel<true><<<dim3(256), 512, 0, stream>>>(
            x, Btf, sw, bw, bias, out);
    } else {
        kan_kernel<false><<<dim3(256), 512, 0, stream>>>(
            x, nullptr, sw, bw, bias, out);
    }
}